// Round 8
// baseline (150.726 us; speedup 1.0000x reference)
//
#include <hip/hip_runtime.h>
#include <math.h>

#define BATCH 8
#define S 512
#define SS (S * S)          // 262144
#define KMAX 16
#define EMPTY_DD 361.1f     // EMPTY_DIST - distance_thre(=1)
#define SENT 1e9f
#define NBLK 256            // 32 blocks/image, 16 rows/block, 1 row/wave
#define IMB 32
#define RPB 16
#define MAGIC1 0x5A5A0000
#define MAGIC2 0x3C3C3C3C
#define SPIN_MAX (1 << 22)

// ws int layout (no init needed — flags are magic-tagged):
// [0..256)       flag1[blk] = MAGIC1 | local_point_count
// [256..4352)    g_pts[blk*16 + k] : packed pixel idx (y*512+x)
// f[4352..4608)  per-block partial lsum
// f[4608..4864)  per-block partial gsum
// f[4864..5120)  per-block partial lmax
// [5120..5376)   flag2[blk] = MAGIC2

__global__ __launch_bounds__(1024, 4) void k_all(const float* __restrict__ pred,
                                                 const float* __restrict__ ptl,
                                                 const float* __restrict__ ori,
                                                 int* __restrict__ wsi,
                                                 float* __restrict__ out) {
    float* wsf = (float*)wsi;
    int tid = threadIdx.x;
    int blk = blockIdx.x;
    int b  = blk >> 5;           // image
    int rg = blk & 31;           // row-group (16 rows)
    int wave = tid >> 6;         // 0..15
    int lane = tid & 63;

    __shared__ int l_cnt;
    __shared__ int l_fnd[16];
    __shared__ int l_list[16];
    __shared__ int l_total;
    __shared__ float sm[16][3];
    __shared__ float fin[8][3];

    if (tid == 0) l_cnt = 0;
    __syncthreads();

    // ---- phase A: scan own 16 rows of pt_label (2 float4 per thread) ----
    {
        int rowbase = rg * (RPB * S);
        const float4* p4 = (const float4*)(ptl + b * SS + rowbase);
#pragma unroll
        for (int q = 0; q < 2; q++) {
            int t = tid + q * 1024;
            float4 v = p4[t];
            float s = v.x + v.y + v.z + v.w;   // labels >= 0
            if (s != 0.0f) {
                int i0 = rowbase + t * 4;
                float c[4] = {v.x, v.y, v.z, v.w};
#pragma unroll
                for (int j = 0; j < 4; j++) {
                    if (c[j] != 0.0f) {
                        int slot = atomicAdd(&l_cnt, 1);
                        if (slot < 16) l_fnd[slot] = i0 + j;
                    }
                }
            }
        }
    }
    __syncthreads();
    int lcnt = l_cnt; if (lcnt > 16) lcnt = 16;
    if (tid < lcnt) wsi[256 + blk * 16 + tid] = l_fnd[tid];
    __threadfence();
    __syncthreads();
    if (tid == 0) {
        __threadfence();
        __hip_atomic_store(&wsi[blk], MAGIC1 | lcnt,
                           __ATOMIC_RELEASE, __HIP_MEMORY_SCOPE_AGENT);
    }

    // ---- per-image point barrier (poll 32 flags of own image) ----
    {
        bool ok = (tid >= IMB);
        for (int g = 0; g < SPIN_MAX; g++) {
            if (!ok) {
                int v = __hip_atomic_load(&wsi[(b << 5) + tid],
                                          __ATOMIC_RELAXED, __HIP_MEMORY_SCOPE_AGENT);
                ok = ((v & 0xFFFF0000) == MAGIC1);
            }
            if (__syncthreads_and(ok)) break;
        }
    }

    // ---- gather this image's points (wave 0, lanes 0..31) ----
    if (wave == 0) {
        int cj = 0;
        if (lane < IMB) {
            int v = __hip_atomic_load(&wsi[(b << 5) + lane],
                                      __ATOMIC_RELAXED, __HIP_MEMORY_SCOPE_AGENT);
            cj = v & 0xFFFF;
        }
        int pre = cj;
#pragma unroll
        for (int d = 1; d < 32; d <<= 1) {
            int t = __shfl_up(pre, d, 64);
            if (lane >= d && lane < 32) pre += t;
        }
        if (lane == 31) l_total = (pre > 16) ? 16 : pre;
        int off = pre - cj;   // exclusive prefix
        if (lane < IMB) {
            for (int k = 0; k < cj; k++) {
                if (off + k < 16)
                    l_list[off + k] = __hip_atomic_load(
                        &wsi[256 + ((b << 5) + lane) * 16 + k],
                        __ATOMIC_RELAXED, __HIP_MEMORY_SCOPE_AGENT);
            }
        }
    }
    __syncthreads();

    int cnt = l_total;
    bool has = cnt > 0;
    float pyk[KMAX], pxk[KMAX];
#pragma unroll
    for (int k = 0; k < KMAX; k++) {
        if (k < cnt) {
            int pk = l_list[k];
            pyk[k] = (float)(pk >> 9);
            pxk[k] = (float)(pk & 511);
        } else { pyk[k] = SENT; pxk[k] = SENT; }
    }

    // ---- phase C: one row per wave — distance + gradient ----
    const float* pb = pred + b * SS;
    const float* ob = ori + b * SS;
    int y = rg * RPB + wave;     // wave-uniform row
    int x0 = lane << 3;
    float fy = (float)y;
    float fx = (float)x0;

    float m[8];
#pragma unroll
    for (int j = 0; j < 8; j++) m[j] = 1e30f;
#pragma unroll
    for (int k = 0; k < KMAX; k++) {
        float dy = fy - pyk[k];
        float dy2 = dy * dy;
        float dx = fx - pxk[k];
#pragma unroll
        for (int j = 0; j < 8; j++) {
            float d = dx + (float)j;
            m[j] = fminf(m[j], fmaf(d, d, dy2));
        }
    }
    float dd[8];
#pragma unroll
    for (int j = 0; j < 8; j++)
        dd[j] = has ? fmaxf(sqrtf(m[j]) - 1.0f, 0.0f) : EMPTY_DD;

    const float4* prow = (const float4*)(pb + y * S + x0);
    float4 pA = prow[0], pB = prow[1];
    float lsum = pA.x * dd[0] + pA.y * dd[1] + pA.z * dd[2] + pA.w * dd[3] +
                 pB.x * dd[4] + pB.y * dd[5] + pB.z * dd[6] + pB.w * dd[7];
    float lmax = fmaxf(fmaxf(fmaxf(dd[0], dd[1]), fmaxf(dd[2], dd[3])),
                       fmaxf(fmaxf(dd[4], dd[5]), fmaxf(dd[6], dd[7])));

    float gsum = 0.0f;
    if (y > 0 && y < S - 1) {    // wave-uniform
        float r[3][10];
#pragma unroll
        for (int ri = 0; ri < 3; ri++) {
            int yy = y - 1 + ri;
            const float4* pr  = (const float4*)(pb + yy * S + x0);
            const float4* orr = (const float4*)(ob + yy * S + x0);
            float4 p0 = (ri == 1) ? pA : pr[0];
            float4 p1 = (ri == 1) ? pB : pr[1];
            float4 o0 = orr[0], o1 = orr[1];
            r[ri][1] = p0.x * o0.x; r[ri][2] = p0.y * o0.y;
            r[ri][3] = p0.z * o0.z; r[ri][4] = p0.w * o0.w;
            r[ri][5] = p1.x * o1.x; r[ri][6] = p1.y * o1.y;
            r[ri][7] = p1.z * o1.z; r[ri][8] = p1.w * o1.w;
            r[ri][0] = __shfl_up(r[ri][8], 1, 64);    // lane0 halo dead (x=0 zeroed)
            r[ri][9] = __shfl_down(r[ri][1], 1, 64);  // lane63 halo dead (x=511 zeroed)
        }
#pragma unroll
        for (int j = 0; j < 8; j++) {
            float a00 = r[0][j], a01 = r[0][j + 1], a02 = r[0][j + 2];
            float a10 = r[1][j],                    a12 = r[1][j + 2];
            float a20 = r[2][j], a21 = r[2][j + 1], a22 = r[2][j + 2];
            float g0 = -a00 + a02 - 2.0f * a10 + 2.0f * a12 - a20 + a22;
            float g1 =  a00 + 2.0f * a01 + a02 - a20 - 2.0f * a21 - a22;
            float g2 =  2.0f * a00 + a01 + a10 - a12 - a21 - 2.0f * a22;
            float g3 =  a01 + 2.0f * a02 - a10 + a12 - 2.0f * a20 - a21;
            float gv = fmaxf(fmaxf(fabsf(g0), fabsf(g1)), fmaxf(fabsf(g2), fabsf(g3)));
            bool edge = (lane == 0 && j == 0) || (lane == 63 && j == 7);
            gsum += edge ? 0.0f : gv;
        }
    }

    // ---- block reduce (16 waves) + publish partials ----
#pragma unroll
    for (int off = 32; off > 0; off >>= 1) {
        lsum += __shfl_down(lsum, off, 64);
        gsum += __shfl_down(gsum, off, 64);
        lmax = fmaxf(lmax, __shfl_down(lmax, off, 64));
    }
    if (lane == 0) { sm[wave][0] = lsum; sm[wave][1] = gsum; sm[wave][2] = lmax; }
    __syncthreads();
    if (wave == 0) {
        float ls = (lane < 16) ? sm[lane][0] : 0.0f;
        float gs = (lane < 16) ? sm[lane][1] : 0.0f;
        float lm = (lane < 16) ? sm[lane][2] : 0.0f;
#pragma unroll
        for (int off = 8; off > 0; off >>= 1) {
            ls += __shfl_down(ls, off, 64);
            gs += __shfl_down(gs, off, 64);
            lm = fmaxf(lm, __shfl_down(lm, off, 64));
        }
        if (lane == 0) {
            wsf[4352 + blk] = ls;
            wsf[4608 + blk] = gs;
            wsf[4864 + blk] = lm;
            __threadfence();
            __hip_atomic_store(&wsi[5120 + blk], MAGIC2,
                               __ATOMIC_RELEASE, __HIP_MEMORY_SCOPE_AGENT);
        }
    }

    // ---- block 0: wait for all partials, finalize ----
    if (blk == 0) {
        bool ok = (tid >= NBLK);
        for (int g = 0; g < SPIN_MAX; g++) {
            if (!ok)
                ok = (__hip_atomic_load(&wsi[5120 + tid],
                                        __ATOMIC_RELAXED, __HIP_MEMORY_SCOPE_AGENT) == MAGIC2);
            if (__syncthreads_and(ok)) break;
        }
        __threadfence();
        // waves 0..7: one image each; lanes 0..31 hold its 32 partials
        if (wave < BATCH) {
            float ls = 0.0f, gs = 0.0f, lm = 0.0f;
            if (lane < IMB) {
                int o = wave * IMB + lane;
                ls = __hip_atomic_load(&wsf[4352 + o], __ATOMIC_RELAXED, __HIP_MEMORY_SCOPE_AGENT);
                gs = __hip_atomic_load(&wsf[4608 + o], __ATOMIC_RELAXED, __HIP_MEMORY_SCOPE_AGENT);
                lm = __hip_atomic_load(&wsf[4864 + o], __ATOMIC_RELAXED, __HIP_MEMORY_SCOPE_AGENT);
            }
#pragma unroll
            for (int off = 16; off > 0; off >>= 1) {
                ls += __shfl_down(ls, off, 64);
                gs += __shfl_down(gs, off, 64);
                lm = fmaxf(lm, __shfl_down(lm, off, 64));
            }
            if (lane == 0) { fin[wave][0] = ls; fin[wave][1] = gs; fin[wave][2] = lm; }
        }
        __syncthreads();
        if (tid == 0) {
            float dl = 0.0f, gl = 0.0f;
#pragma unroll
            for (int bb = 0; bb < BATCH; bb++) {
                dl += fin[bb][0] / fin[bb][2];
                gl += fin[bb][1];
            }
            out[0] = dl / (float)(SS * BATCH);
            out[1] = gl / (float)(SS * BATCH);
        }
    }
}

extern "C" void kernel_launch(void* const* d_in, const int* in_sizes, int n_in,
                              void* d_out, int out_size, void* d_ws, size_t ws_size,
                              hipStream_t stream) {
    const float* pred = (const float*)d_in[0];
    const float* ptl  = (const float*)d_in[1];
    const float* ori  = (const float*)d_in[2];
    float* out = (float*)d_out;
    int* wsi = (int*)d_ws;

    k_all<<<NBLK, 1024, 0, stream>>>(pred, ptl, ori, wsi, out);
}

// Round 9
// 109.740 us; speedup vs baseline: 1.3735x; 1.3735x over previous
//
#include <hip/hip_runtime.h>
#include <math.h>

#define BATCH 8
#define S 512
#define SS (S * S)          // 262144
#define KMAX 16
#define EMPTY_DD 361.1f     // EMPTY_DIST - distance_thre(=1)
#define SENT 1e9f
#define NBLK 256            // 32 blocks/image, 16 rows/block
#define IMB 32
#define RPB 16
#define MAGIC1 0x5A5A0000
#define MAGIC2 0x3C3C3C3C
#define SPIN_MAX (1 << 22)

// ws int layout (NO initialization required — flags are magic-tagged):
// [0..256)       flag1[blk] = MAGIC1 | local_point_count
// [256..4352)    g_pts[blk*16 + k] : packed pixel idx (y*512+x) within image
// f[4352..4608)  per-block partial lsum
// f[4608..4864)  per-block partial gsum
// f[4864..5120)  per-block partial lmax
// [5120..5376)   flag2[blk] = MAGIC2

__global__ __launch_bounds__(256, 2) void k_all(const float* __restrict__ pred,
                                                const float* __restrict__ ptl,
                                                const float* __restrict__ ori,
                                                int* __restrict__ wsi,
                                                float* __restrict__ out) {
    float* wsf = (float*)wsi;
    int tid = threadIdx.x;
    int blk = blockIdx.x;
    int b  = blk >> 5;           // image
    int rg = blk & 31;           // row-group (16 rows)
    int wave = tid >> 6;
    int lane = tid & 63;

    __shared__ int l_cnt;
    __shared__ int l_fnd[16];
    __shared__ int l_list[16];
    __shared__ int l_total;
    __shared__ float sm[4][3];
    __shared__ float fin[8][3];

    if (tid == 0) l_cnt = 0;
    __syncthreads();

    // ---- phase A: scan own 16 rows of pt_label for highlight points ----
    {
        const float4* p4 = (const float4*)(ptl + b * SS + rg * (RPB * S)) + tid * 8;
#pragma unroll
        for (int q = 0; q < 8; q++) {
            float4 v = p4[q];
            float s = v.x + v.y + v.z + v.w;   // labels are >= 0
            if (s != 0.0f) {
                int i0 = rg * (RPB * S) + tid * 32 + q * 4;
                float c[4] = {v.x, v.y, v.z, v.w};
#pragma unroll
                for (int j = 0; j < 4; j++) {
                    if (c[j] != 0.0f) {
                        int slot = atomicAdd(&l_cnt, 1);
                        if (slot < 16) l_fnd[slot] = i0 + j;
                    }
                }
            }
        }
    }
    __syncthreads();
    int lcnt = l_cnt; if (lcnt > 16) lcnt = 16;
    if (tid < lcnt) wsi[256 + blk * 16 + tid] = l_fnd[tid];
    __threadfence();
    __syncthreads();
    if (tid == 0) {
        __threadfence();
        __hip_atomic_store(&wsi[blk], MAGIC1 | lcnt,
                           __ATOMIC_RELEASE, __HIP_MEMORY_SCOPE_AGENT);
    }

    // ---- per-image point barrier (bounded spin; all blocks co-resident) ----
    {
        bool ok = (tid >= IMB);
        for (int g = 0; g < SPIN_MAX; g++) {
            if (!ok) {
                int v = __hip_atomic_load(&wsi[(b << 5) + tid],
                                          __ATOMIC_RELAXED, __HIP_MEMORY_SCOPE_AGENT);
                ok = ((v & 0xFFFF0000) == MAGIC1);
            }
            if (__syncthreads_and(ok)) break;
        }
    }

    // ---- gather this image's points (wave 0, lanes 0..31) ----
    if (wave == 0) {
        int cj = 0;
        if (lane < IMB) {
            int v = __hip_atomic_load(&wsi[(b << 5) + lane],
                                      __ATOMIC_RELAXED, __HIP_MEMORY_SCOPE_AGENT);
            cj = v & 0xFFFF;
        }
        int pre = cj;
#pragma unroll
        for (int d = 1; d < 32; d <<= 1) {
            int t = __shfl_up(pre, d, 64);
            if (lane >= d && lane < 32) pre += t;
        }
        if (lane == 31) l_total = (pre > 16) ? 16 : pre;
        int off = pre - cj;   // exclusive prefix
        if (lane < IMB) {
            for (int k = 0; k < cj; k++) {
                if (off + k < 16)
                    l_list[off + k] = __hip_atomic_load(
                        &wsi[256 + ((b << 5) + lane) * 16 + k],
                        __ATOMIC_RELAXED, __HIP_MEMORY_SCOPE_AGENT);
            }
        }
    }
    __syncthreads();

    int cnt = l_total;
    bool has = cnt > 0;
    float pyk[KMAX], pxk[KMAX];
#pragma unroll
    for (int k = 0; k < KMAX; k++) {
        if (k < cnt) {
            int pk = l_list[k];
            pyk[k] = (float)(pk >> 9);
            pxk[k] = (float)(pk & 511);
        } else { pyk[k] = SENT; pxk[k] = SENT; }
    }

    // ---- phase C: fused distance + gradient, 4 rows per wave ----
    const float* pb = pred + b * SS;
    const float* ob = ori + b * SS;
    int x0 = lane << 3;
    float fx = (float)x0;
    float lsum = 0.0f, gsum = 0.0f, lmax = 0.0f;
    int ybase = rg * RPB + wave * 4;

    for (int it = 0; it < 4; it++) {
        int y = ybase + it;      // wave-uniform
        float fy = (float)y;

        float m[8];
#pragma unroll
        for (int j = 0; j < 8; j++) m[j] = 1e30f;
#pragma unroll
        for (int k = 0; k < KMAX; k++) {
            float dy = fy - pyk[k];
            float dy2 = dy * dy;
            float dx = fx - pxk[k];
#pragma unroll
            for (int j = 0; j < 8; j++) {
                float d = dx + (float)j;
                m[j] = fminf(m[j], fmaf(d, d, dy2));
            }
        }
        float dd[8];
#pragma unroll
        for (int j = 0; j < 8; j++)
            dd[j] = has ? fmaxf(sqrtf(m[j]) - 1.0f, 0.0f) : EMPTY_DD;

        const float4* prow = (const float4*)(pb + y * S + x0);
        float4 pA = prow[0], pB = prow[1];
        lsum += pA.x * dd[0] + pA.y * dd[1] + pA.z * dd[2] + pA.w * dd[3] +
                pB.x * dd[4] + pB.y * dd[5] + pB.z * dd[6] + pB.w * dd[7];
        float rmax = fmaxf(fmaxf(fmaxf(dd[0], dd[1]), fmaxf(dd[2], dd[3])),
                           fmaxf(fmaxf(dd[4], dd[5]), fmaxf(dd[6], dd[7])));
        lmax = fmaxf(lmax, rmax);

        if (y > 0 && y < S - 1) {
            float r[3][10];
#pragma unroll
            for (int ri = 0; ri < 3; ri++) {
                int yy = y - 1 + ri;
                const float4* pr  = (const float4*)(pb + yy * S + x0);
                const float4* orr = (const float4*)(ob + yy * S + x0);
                float4 p0 = (ri == 1) ? pA : pr[0];
                float4 p1 = (ri == 1) ? pB : pr[1];
                float4 o0 = orr[0], o1 = orr[1];
                r[ri][1] = p0.x * o0.x; r[ri][2] = p0.y * o0.y;
                r[ri][3] = p0.z * o0.z; r[ri][4] = p0.w * o0.w;
                r[ri][5] = p1.x * o1.x; r[ri][6] = p1.y * o1.y;
                r[ri][7] = p1.z * o1.z; r[ri][8] = p1.w * o1.w;
                r[ri][0] = __shfl_up(r[ri][8], 1, 64);    // lane0 value dead (x=0 zeroed)
                r[ri][9] = __shfl_down(r[ri][1], 1, 64);  // lane63 value dead (x=511 zeroed)
            }
#pragma unroll
            for (int j = 0; j < 8; j++) {
                float a00 = r[0][j], a01 = r[0][j + 1], a02 = r[0][j + 2];
                float a10 = r[1][j],                    a12 = r[1][j + 2];
                float a20 = r[2][j], a21 = r[2][j + 1], a22 = r[2][j + 2];
                float g0 = -a00 + a02 - 2.0f * a10 + 2.0f * a12 - a20 + a22;
                float g1 =  a00 + 2.0f * a01 + a02 - a20 - 2.0f * a21 - a22;
                float g2 =  2.0f * a00 + a01 + a10 - a12 - a21 - 2.0f * a22;
                float g3 =  a01 + 2.0f * a02 - a10 + a12 - 2.0f * a20 - a21;
                float gv = fmaxf(fmaxf(fabsf(g0), fabsf(g1)), fmaxf(fabsf(g2), fabsf(g3)));
                bool edge = (lane == 0 && j == 0) || (lane == 63 && j == 7);
                gsum += edge ? 0.0f : gv;
            }
        }
    }

    // ---- block reduce + publish partials ----
#pragma unroll
    for (int off = 32; off > 0; off >>= 1) {
        lsum += __shfl_down(lsum, off, 64);
        gsum += __shfl_down(gsum, off, 64);
        lmax = fmaxf(lmax, __shfl_down(lmax, off, 64));
    }
    if (lane == 0) { sm[wave][0] = lsum; sm[wave][1] = gsum; sm[wave][2] = lmax; }
    __syncthreads();
    if (tid == 0) {
#pragma unroll
        for (int w = 1; w < 4; w++) {
            lsum += sm[w][0];
            gsum += sm[w][1];
            lmax = fmaxf(lmax, sm[w][2]);
        }
        wsf[4352 + blk] = lsum;
        wsf[4608 + blk] = gsum;
        wsf[4864 + blk] = lmax;
        __threadfence();
        __hip_atomic_store(&wsi[5120 + blk], MAGIC2,
                           __ATOMIC_RELEASE, __HIP_MEMORY_SCOPE_AGENT);
    }

    // ---- block 0: wait for all partials, finalize ----
    if (blk == 0) {
        bool ok = false;
        for (int g = 0; g < SPIN_MAX; g++) {
            if (!ok)
                ok = (__hip_atomic_load(&wsi[5120 + tid],
                                        __ATOMIC_RELAXED, __HIP_MEMORY_SCOPE_AGENT) == MAGIC2);
            if (__syncthreads_and(ok)) break;
        }
        __threadfence();
        float ls = __hip_atomic_load(&wsf[4352 + tid], __ATOMIC_RELAXED, __HIP_MEMORY_SCOPE_AGENT);
        float gs = __hip_atomic_load(&wsf[4608 + tid], __ATOMIC_RELAXED, __HIP_MEMORY_SCOPE_AGENT);
        float lm = __hip_atomic_load(&wsf[4864 + tid], __ATOMIC_RELAXED, __HIP_MEMORY_SCOPE_AGENT);
        // segment-reduce 32-lane groups (one image per group of 32 tids)
#pragma unroll
        for (int off = 16; off > 0; off >>= 1) {
            ls += __shfl_down(ls, off, 32);
            gs += __shfl_down(gs, off, 32);
            lm = fmaxf(lm, __shfl_down(lm, off, 32));
        }
        if ((lane & 31) == 0) {
            int img = (wave << 1) | (lane >> 5);
            fin[img][0] = ls; fin[img][1] = gs; fin[img][2] = lm;
        }
        __syncthreads();
        if (tid == 0) {
            float dl = 0.0f, gl = 0.0f;
#pragma unroll
            for (int bb = 0; bb < BATCH; bb++) {
                dl += fin[bb][0] / fin[bb][2];
                gl += fin[bb][1];
            }
            out[0] = dl / (float)(SS * BATCH);
            out[1] = gl / (float)(SS * BATCH);
        }
    }
}

extern "C" void kernel_launch(void* const* d_in, const int* in_sizes, int n_in,
                              void* d_out, int out_size, void* d_ws, size_t ws_size,
                              hipStream_t stream) {
    const float* pred = (const float*)d_in[0];
    const float* ptl  = (const float*)d_in[1];
    const float* ori  = (const float*)d_in[2];
    float* out = (float*)d_out;
    int* wsi = (int*)d_ws;

    k_all<<<NBLK, 256, 0, stream>>>(pred, ptl, ori, wsi, out);
}